// Round 2
// 3279.729 us; speedup vs baseline: 1.0933x; 1.0933x over previous
//
#include <hip/hip_runtime.h>

#define BB 256
#define TT 2048
#define II 64
#define HH 256
#define OO 64
#define FF 16

// ---------------------------------------------------------------------------
// R6 theory: old structure was LDS-return-path bound: 52 broadcast
// ds_read_b128/wave/step x 8 waves x ~10.6cyc = ~4400 cyc/step = observed.
// Fix: 4 output rows per thread (j0..j0+3) x 8-way K-split (kg) -> each LDS
// read feeds 4 rows AND h0 reads feed both layers: 9 b128/wave/step.
// K-partials reduced in-wave: quad_perm DPP (xor1,xor2) + ds_swizzle (xor4).
// Layer 1 runs one step behind layer 0 (reads committed h0_{t-1}) so both
// layers' dots are one phase: ONE barrier/step + double-buffered h0/h1/x.
// Weights stay pinned in VGPRs (208 ints/thread, invariant); 256-reg budget
// pinned via amdgpu_waves_per_eu(2,2).
// R7: R6 bench died with "container failed twice" (infra). Audit found no
// OOB / deadlock / divergent-barrier hazard; resubmitting unchanged.
// ---------------------------------------------------------------------------

// LDS byte layout: two state buffers then the FC tail.
//   h0: 8 slices x 80B @ 0     (64B data + 16B pad -> 8 distinct bank groups)
//   h1: 8 slices x 80B @ 704   (bank offset +16 vs h0 -> write conflict-free)
//   x : 8 slices x 16B @ 1344
#define BUFSZ 2048
#define BUF0 0
#define BUF1 BUFSZ
#define H1OFF 704
#define XOFF 1344
#define SLICE 80
#define TAILOFF (2 * BUFSZ)
#define LDSBYTES (TAILOFF + FF * HH * 2)

typedef _Float16 h2 __attribute__((ext_vector_type(2)));
typedef _Float16 h8 __attribute__((ext_vector_type(8)));

__device__ __forceinline__ float fdot2f(h2 a, h2 b, float c) {
#if __has_builtin(__builtin_amdgcn_fdot2)
  return __builtin_amdgcn_fdot2(a, b, c, false);  // v_dot2_f32_f16
#else
  return c + (float)a[0] * (float)b[0] + (float)a[1] * (float)b[1];
#endif
}

__device__ __forceinline__ float fast_tanh(float z) {
  float e = __builtin_amdgcn_exp2f(z * 2.885390081777927f);
  return 1.0f - 2.0f * __builtin_amdgcn_rcpf(e + 1.0f);
}

__device__ __forceinline__ h2 i2h(int w) {
  union { int i; h2 h; } u; u.i = w; return u.h;
}
__device__ __forceinline__ int pk2i(const float* p) {
  union { h2 h; int i; } u; u.h[0] = (_Float16)p[0]; u.h[1] = (_Float16)p[1];
  return u.i;
}

// butterfly helpers: all lanes of each 8-lane segment end with the full sum
template <int CTRL>
__device__ __forceinline__ float dpp_add(float v) {
  union { float f; int i; } a, r;
  a.f = v;
  r.i = __builtin_amdgcn_update_dpp(0, a.i, CTRL, 0xF, 0xF, true);
  return v + r.f;
}
__device__ __forceinline__ float swz4_add(float v) {
  union { float f; int i; } a, r;
  a.f = v;
  r.i = __builtin_amdgcn_ds_swizzle(a.i, 0x101F);  // lane ^ 4
  return v + r.f;
}

// One step: dots for layer0(t) + layer1(t-1) from RB, in-wave reduce, commit
// h0_t and h1_{t-1} into WB, one barrier. Lane (kg&3, kg>>2) commits row
// j0+(kg&3) of layer kg>>2.
#define RNN_STEP(T, RB, WB)                                                    \
  {                                                                            \
    float xn = 0.f;                                                            \
    if (kg == 0) {                                                             \
      int tn = (T) + 1 < TT ? (T) + 1 : (T);                                   \
      xn = xrow[(size_t)tn * II + xi];                                         \
    }                                                                          \
    float a0[4] = {0.f, 0.f, 0.f, 0.f};                                        \
    float a1[4] = {0.f, 0.f, 0.f, 0.f};                                        \
    {                                                                          \
      const int4 xv = *(const int4*)(xaddr + (RB) + XOFF);                     \
      _Pragma("unroll") for (int r = 0; r < 4; ++r) {                          \
        a0[r] = fdot2f(i2h(xv.x), i2h(w0x[r][0]), a0[r]);                      \
        a0[r] = fdot2f(i2h(xv.y), i2h(w0x[r][1]), a0[r]);                      \
        a0[r] = fdot2f(i2h(xv.z), i2h(w0x[r][2]), a0[r]);                      \
        a0[r] = fdot2f(i2h(xv.w), i2h(w0x[r][3]), a0[r]);                      \
      }                                                                        \
    }                                                                          \
    _Pragma("unroll") for (int c = 0; c < 4; ++c) {                            \
      const int4 v = *(const int4*)(haddr + (RB) + c * 16);                    \
      _Pragma("unroll") for (int r = 0; r < 4; ++r) {                          \
        a0[r] = fdot2f(i2h(v.x), i2h(w0h[r][4 * c + 0]), a0[r]);               \
        a0[r] = fdot2f(i2h(v.y), i2h(w0h[r][4 * c + 1]), a0[r]);               \
        a0[r] = fdot2f(i2h(v.z), i2h(w0h[r][4 * c + 2]), a0[r]);               \
        a0[r] = fdot2f(i2h(v.w), i2h(w0h[r][4 * c + 3]), a0[r]);               \
        a1[r] = fdot2f(i2h(v.x), i2h(w1g[r][4 * c + 0]), a1[r]);               \
        a1[r] = fdot2f(i2h(v.y), i2h(w1g[r][4 * c + 1]), a1[r]);               \
        a1[r] = fdot2f(i2h(v.z), i2h(w1g[r][4 * c + 2]), a1[r]);               \
        a1[r] = fdot2f(i2h(v.w), i2h(w1g[r][4 * c + 3]), a1[r]);               \
      }                                                                        \
    }                                                                          \
    _Pragma("unroll") for (int c = 0; c < 4; ++c) {                            \
      const int4 v = *(const int4*)(haddr + (RB) + H1OFF + c * 16);            \
      _Pragma("unroll") for (int r = 0; r < 4; ++r) {                          \
        a1[r] = fdot2f(i2h(v.x), i2h(w1h[r][4 * c + 0]), a1[r]);               \
        a1[r] = fdot2f(i2h(v.y), i2h(w1h[r][4 * c + 1]), a1[r]);               \
        a1[r] = fdot2f(i2h(v.z), i2h(w1h[r][4 * c + 2]), a1[r]);               \
        a1[r] = fdot2f(i2h(v.w), i2h(w1h[r][4 * c + 3]), a1[r]);               \
      }                                                                        \
    }                                                                          \
    _Pragma("unroll") for (int r = 0; r < 4; ++r) {                            \
      a0[r] = dpp_add<0xB1>(a0[r]);                                            \
      a0[r] = dpp_add<0x4E>(a0[r]);                                            \
      a0[r] = swz4_add(a0[r]);                                                 \
      a1[r] = dpp_add<0xB1>(a1[r]);                                            \
      a1[r] = dpp_add<0x4E>(a1[r]);                                            \
      a1[r] = swz4_add(a1[r]);                                                 \
    }                                                                          \
    float s0 = (kg & 1) ? a0[1] : a0[0];                                       \
    float s1 = (kg & 1) ? a0[3] : a0[2];                                       \
    float u0 = (kg & 1) ? a1[1] : a1[0];                                       \
    float u1 = (kg & 1) ? a1[3] : a1[2];                                       \
    float v0 = (kg & 2) ? s1 : s0;                                             \
    float v1 = (kg & 2) ? u1 : u0;                                             \
    float hnew = fast_tanh((L ? v1 : v0) + mybias);                            \
    hlast = hnew;                                                              \
    if ((T) > 0 || L == 0) *(_Float16*)(waddr + (WB)) = (_Float16)hnew;        \
    if (L == 1 && (T) >= TT - FF + 1)                                          \
      *(_Float16*)(tailaddr + ((T) - (TT - FF + 1)) * (HH * 2)) =              \
          (_Float16)hnew;                                                      \
    if (kg == 0) *(_Float16*)(lb + (WB) + XOFF + xi * 2) = (_Float16)xn;       \
    __syncthreads();                                                           \
  }

__global__ __attribute__((amdgpu_flat_work_group_size(512, 512),
                          amdgpu_waves_per_eu(2, 2)))
void rnn_fused(const float* __restrict__ x, const float* __restrict__ hidden,
               const float* __restrict__ Wih0, const float* __restrict__ Whh0,
               const float* __restrict__ bih0, const float* __restrict__ bhh0,
               const float* __restrict__ Wih1, const float* __restrict__ Whh1,
               const float* __restrict__ bih1, const float* __restrict__ bhh1,
               const float* __restrict__ fcW, const float* __restrict__ fcb,
               float* __restrict__ out)
{
  const int tid = threadIdx.x;
  const int b = blockIdx.x;
  const int lane = tid & 63;
  const int kg = lane & 7;                      // K-group 0..7
  const int rg = (tid >> 6) * 8 + (lane >> 3);  // row-group 0..63
  const int j0 = rg * 4;                        // first of 4 owned rows
  const int L = kg >> 2;                        // commit layer of this lane
  const int cj = j0 + (kg & 3);                 // committed row
  const int xi = tid >> 3;                      // x element for kg==0 lanes

  __shared__ __align__(16) char lds[LDSBYTES];
  char* lb = (char*)lds;

  // ---- weights for rows j0..j0+3, K-slice kg -> 208 pinned VGPRs ----
  int w0x[4][4], w0h[4][16], w1g[4][16], w1h[4][16];
#pragma unroll
  for (int r = 0; r < 4; ++r) {
    const float* p0 = Wih0 + (size_t)(j0 + r) * II + kg * 8;
#pragma unroll
    for (int m = 0; m < 4; ++m) w0x[r][m] = pk2i(p0 + 2 * m);
    const float* p1 = Whh0 + (size_t)(j0 + r) * HH + kg * 32;
#pragma unroll
    for (int m = 0; m < 16; ++m) w0h[r][m] = pk2i(p1 + 2 * m);
    const float* p2 = Wih1 + (size_t)(j0 + r) * HH + kg * 32;
#pragma unroll
    for (int m = 0; m < 16; ++m) w1g[r][m] = pk2i(p2 + 2 * m);
    const float* p3 = Whh1 + (size_t)(j0 + r) * HH + kg * 32;
#pragma unroll
    for (int m = 0; m < 16; ++m) w1h[r][m] = pk2i(p3 + 2 * m);
  }
  // opaque pass-through: no remat of the weight loads inside the t-loop
#pragma unroll
  for (int r = 0; r < 4; ++r) {
#pragma unroll
    for (int m = 0; m < 4; ++m) asm volatile("" : "+v"(w0x[r][m]));
#pragma unroll
    for (int m = 0; m < 16; ++m) {
      asm volatile("" : "+v"(w0h[r][m]));
      asm volatile("" : "+v"(w1g[r][m]));
      asm volatile("" : "+v"(w1h[r][m]));
    }
  }
  float mybias = L ? (bih1[cj] + bhh1[cj]) : (bih0[cj] + bhh0[cj]);
  asm volatile("" : "+v"(mybias));

  // ---- loop-invariant LDS addresses ----
  const char* haddr = lb + kg * SLICE;  // +RB(+H1OFF)+c*16
  const char* xaddr = lb + kg * 16;     // +RB+XOFF
  char* waddr = lb + L * H1OFF + (cj >> 5) * SLICE + (cj & 31) * 2;  // +WB
  char* tailaddr = lb + TAILOFF + cj * 2;  // +f*512, L==1 lanes only

  // ---- init state: BUF0 <- {h0_init, h1_init, x_0}; BUF1.h1 <- h1_init
  // (step 0 commits h0_0+x_1 to BUF1 but skips h1, so BUF1.h1 must hold the
  //  true h1_init that step 1's layer-1 dots consume) ----
  if (tid < HH) {
    char* p = lb + (tid >> 5) * SLICE + (tid & 31) * 2;
    _Float16 h0v = (_Float16)hidden[(size_t)b * HH + tid];
    _Float16 h1v = (_Float16)hidden[(size_t)(BB + b) * HH + tid];
    *(_Float16*)(p + BUF0) = h0v;
    *(_Float16*)(p + BUF0 + H1OFF) = h1v;
    *(_Float16*)(p + BUF1 + H1OFF) = h1v;
  }
  const float* xrow = x + (size_t)b * TT * II;
  if (tid < II) *(_Float16*)(lb + BUF0 + XOFF + tid * 2) = (_Float16)xrow[tid];
  float hlast = 0.f, h1last = 0.f;
  __syncthreads();

  // ---- main loop: 1 barrier/step, unroll x2 so RB/WB are immediates ----
#pragma unroll 1
  for (int t = 0; t < TT; t += 2) {
    RNN_STEP(t, BUF0, BUF1)
    RNN_STEP(t + 1, BUF1, BUF0)
  }

  // ---- epilogue: h1_{TT-1} from BUF0 (holds h0_{TT-1}, h1_{TT-2}) ----
  {
    float a1[4] = {0.f, 0.f, 0.f, 0.f};
#pragma unroll
    for (int c = 0; c < 4; ++c) {
      const int4 v = *(const int4*)(haddr + BUF0 + c * 16);
#pragma unroll
      for (int r = 0; r < 4; ++r) {
        a1[r] = fdot2f(i2h(v.x), i2h(w1g[r][4 * c + 0]), a1[r]);
        a1[r] = fdot2f(i2h(v.y), i2h(w1g[r][4 * c + 1]), a1[r]);
        a1[r] = fdot2f(i2h(v.z), i2h(w1g[r][4 * c + 2]), a1[r]);
        a1[r] = fdot2f(i2h(v.w), i2h(w1g[r][4 * c + 3]), a1[r]);
      }
    }
#pragma unroll
    for (int c = 0; c < 4; ++c) {
      const int4 v = *(const int4*)(haddr + BUF0 + H1OFF + c * 16);
#pragma unroll
      for (int r = 0; r < 4; ++r) {
        a1[r] = fdot2f(i2h(v.x), i2h(w1h[r][4 * c + 0]), a1[r]);
        a1[r] = fdot2f(i2h(v.y), i2h(w1h[r][4 * c + 1]), a1[r]);
        a1[r] = fdot2f(i2h(v.z), i2h(w1h[r][4 * c + 2]), a1[r]);
        a1[r] = fdot2f(i2h(v.w), i2h(w1h[r][4 * c + 3]), a1[r]);
      }
    }
#pragma unroll
    for (int r = 0; r < 4; ++r) {
      a1[r] = dpp_add<0xB1>(a1[r]);
      a1[r] = dpp_add<0x4E>(a1[r]);
      a1[r] = swz4_add(a1[r]);
    }
    float u0 = (kg & 1) ? a1[1] : a1[0];
    float u1 = (kg & 1) ? a1[3] : a1[2];
    float v1 = (kg & 2) ? u1 : u0;
    float h1e = fast_tanh(v1 + mybias);  // valid on L==1 lanes
    h1last = h1e;
    if (L == 1) *(_Float16*)(tailaddr + (FF - 1) * (HH * 2)) = (_Float16)h1e;
  }
  __syncthreads();

  // ---- new_hidden [2,B,H] f32 at flat offset B*F*O (f32-accurate tanh) ----
  if (L == 0) out[BB * FF * OO + (size_t)b * HH + cj] = hlast;
  else        out[BB * FF * OO + (size_t)(BB + b) * HH + cj] = h1last;

  // ---- out[b,f,o] = tail[f] . fcW[o,:] + fcb[o]  ([B,F,O] f32) ----
  const int o = tid & 63;
  const int fg = tid >> 6;  // f = 2*fg, 2*fg+1
  const _Float16* tp = (const _Float16*)(lb + TAILOFF);
  float acc0 = 0.f, acc1 = 0.f;
  const float* wrow = fcW + o * HH;
  for (int c = 0; c < HH / 8; ++c) {
    float wv[8];
#pragma unroll
    for (int k = 0; k < 8; ++k) wv[k] = wrow[8 * c + k];
    h8 q0 = *(const h8*)(tp + (2 * fg) * HH + 8 * c);
    h8 q1 = *(const h8*)(tp + (2 * fg + 1) * HH + 8 * c);
#pragma unroll
    for (int e = 0; e < 8; ++e) {
      acc0 += (float)q0[e] * wv[e];
      acc1 += (float)q1[e] * wv[e];
    }
  }
  const float bo = fcb[o];
  out[((size_t)b * FF + 2 * fg) * OO + o] = acc0 + bo;
  out[((size_t)b * FF + 2 * fg + 1) * OO + o] = acc1 + bo;
}

extern "C" void kernel_launch(void* const* d_in, const int* in_sizes, int n_in,
                              void* d_out, int out_size, void* d_ws, size_t ws_size,
                              hipStream_t stream) {
  (void)in_sizes; (void)n_in; (void)d_ws; (void)ws_size; (void)out_size;
  rnn_fused<<<dim3(BB), dim3(512), 0, stream>>>(
      (const float*)d_in[0],  (const float*)d_in[1],
      (const float*)d_in[2],  (const float*)d_in[3],
      (const float*)d_in[4],  (const float*)d_in[5],
      (const float*)d_in[6],  (const float*)d_in[7],
      (const float*)d_in[8],  (const float*)d_in[9],
      (const float*)d_in[10], (const float*)d_in[11],
      (float*)d_out);
}

// Round 3
// 3145.774 us; speedup vs baseline: 1.1399x; 1.0426x over previous
//
#include <hip/hip_runtime.h>

#define BB 256
#define TT 2048
#define II 64
#define HH 256
#define OO 64
#define FF 16

// ---------------------------------------------------------------------------
// R8: R6/R7 post-mortem: VGPR_Count stayed 128 -> the 208 pinned weights went
// to AGPRs (unified file 128+128); every fdot2 use paid a v_accvgpr_read
// (~1200 extra VALU cyc/step/SIMD), and the 8-way reduce's ds_swizzle sat in
// a serial tail that both barrier-locked waves stalled on together.
// Fixes:
//  (a) every dot is inline-asm v_dot2_f32_f16 with "v"-constrained weight
//      operands -> 208 arch-VGPR uses per iteration makes AGPR residency
//      unprofitable; demand ~240 <= 256 budget @ waves_per_eu(2,2).
//  (b) 4-way K-split x 2 rows x 2 layers per thread (same 208 weight ints):
//      reduce = 2 quad_perm DPPs (xor1,xor2), NO ds_swizzle; every thread
//      commits exactly one (row,layer) -> no commit divergence.
//  (c) h-slices padded to 144B so the 4 kg slice bases hit disjoint banks
//      (kg*36 words -> banks kg*4; b128 spans 4 -> lanes cover banks 0..15).
// ---------------------------------------------------------------------------

// LDS per state buffer: h0 4x144 @0, h1 4x144 @576, x 4x32 @1152 -> 1280 B.
#define BUFSZ 1280
#define BUF0 0
#define BUF1 BUFSZ
#define H1OFF 576
#define XOFF 1152
#define HSL 144
#define XSL 32
#define TAILOFF (2 * BUFSZ)
#define LDSBYTES (TAILOFF + FF * HH * 2)

typedef _Float16 h8 __attribute__((ext_vector_type(8)));

// D = S0.h0*S1.h0 + S0.h1*S1.h1 + D  (v_dot2_f32_f16). Weight operand has a
// hard "v" constraint at every use -> allocator must keep weights in arch
// VGPRs (AGPR residency would cost an accvgpr_read per dot).
__device__ __forceinline__ void adot(float& acc, int hv, int wv) {
  asm("v_dot2_f32_f16 %0, %1, %2, %0" : "+v"(acc) : "v"(hv), "v"(wv));
}

__device__ __forceinline__ float fast_tanh(float z) {
  float e = __builtin_amdgcn_exp2f(z * 2.885390081777927f);
  return 1.0f - 2.0f * __builtin_amdgcn_rcpf(e + 1.0f);
}

__device__ __forceinline__ int pk2i(const float* p) {
  union { _Float16 h[2]; int i; } u;
  u.h[0] = (_Float16)p[0]; u.h[1] = (_Float16)p[1];
  return u.i;
}

// quad_perm butterfly add: 0xB1 = xor1, 0x4E = xor2. After both, all 4 lanes
// of each quad hold the quad-sum. Pure VALU -> no lgkm wait in the tail.
template <int CTRL>
__device__ __forceinline__ float dpp_add(float v) {
  union { float f; int i; } a, r;
  a.f = v;
  r.i = __builtin_amdgcn_update_dpp(0, a.i, CTRL, 0xF, 0xF, true);
  return v + r.f;
}

// One step: layer0(t) + layer1(t-1) dots from RB, quad reduce, commit h0_t,
// h1_{t-1}, x_{t+1} into WB, one barrier. Lane kg of each quad commits
// (row j0+(kg&1), layer kg>>1).
#define RNN_STEP(T, RB, WB)                                                    \
  {                                                                            \
    float xn = 0.f;                                                            \
    if ((tid & 7) == 0) {                                                      \
      int tn = (T) + 1 < TT ? (T) + 1 : (T);                                   \
      xn = xrow[(size_t)tn * II + xi];                                         \
    }                                                                          \
    float a00 = 0.f, a01 = 0.f, a10 = 0.f, a11 = 0.f;                          \
    _Pragma("unroll") for (int c = 0; c < 2; ++c) {                            \
      const int4 v = *(const int4*)(xaddr + (RB) + c * 16);                    \
      adot(a00, v.x, w0x[0][4 * c + 0]); adot(a00, v.y, w0x[0][4 * c + 1]);    \
      adot(a00, v.z, w0x[0][4 * c + 2]); adot(a00, v.w, w0x[0][4 * c + 3]);    \
      adot(a01, v.x, w0x[1][4 * c + 0]); adot(a01, v.y, w0x[1][4 * c + 1]);    \
      adot(a01, v.z, w0x[1][4 * c + 2]); adot(a01, v.w, w0x[1][4 * c + 3]);    \
    }                                                                          \
    _Pragma("unroll") for (int c = 0; c < 8; ++c) {                            \
      const int4 v = *(const int4*)(h0addr + (RB) + c * 16);                   \
      adot(a00, v.x, w0h[0][4 * c + 0]); adot(a00, v.y, w0h[0][4 * c + 1]);    \
      adot(a00, v.z, w0h[0][4 * c + 2]); adot(a00, v.w, w0h[0][4 * c + 3]);    \
      adot(a01, v.x, w0h[1][4 * c + 0]); adot(a01, v.y, w0h[1][4 * c + 1]);    \
      adot(a01, v.z, w0h[1][4 * c + 2]); adot(a01, v.w, w0h[1][4 * c + 3]);    \
      adot(a10, v.x, w1g[0][4 * c + 0]); adot(a10, v.y, w1g[0][4 * c + 1]);    \
      adot(a10, v.z, w1g[0][4 * c + 2]); adot(a10, v.w, w1g[0][4 * c + 3]);    \
      adot(a11, v.x, w1g[1][4 * c + 0]); adot(a11, v.y, w1g[1][4 * c + 1]);    \
      adot(a11, v.z, w1g[1][4 * c + 2]); adot(a11, v.w, w1g[1][4 * c + 3]);    \
    }                                                                          \
    _Pragma("unroll") for (int c = 0; c < 8; ++c) {                            \
      const int4 v = *(const int4*)(h0addr + (RB) + H1OFF + c * 16);           \
      adot(a10, v.x, w1h[0][4 * c + 0]); adot(a10, v.y, w1h[0][4 * c + 1]);    \
      adot(a10, v.z, w1h[0][4 * c + 2]); adot(a10, v.w, w1h[0][4 * c + 3]);    \
      adot(a11, v.x, w1h[1][4 * c + 0]); adot(a11, v.y, w1h[1][4 * c + 1]);    \
      adot(a11, v.z, w1h[1][4 * c + 2]); adot(a11, v.w, w1h[1][4 * c + 3]);    \
    }                                                                          \
    a00 = dpp_add<0xB1>(a00); a00 = dpp_add<0x4E>(a00);                        \
    a01 = dpp_add<0xB1>(a01); a01 = dpp_add<0x4E>(a01);                        \
    a10 = dpp_add<0xB1>(a10); a10 = dpp_add<0x4E>(a10);                        \
    a11 = dpp_add<0xB1>(a11); a11 = dpp_add<0x4E>(a11);                        \
    float v0 = (kg & 1) ? a01 : a00;                                           \
    float v1 = (kg & 1) ? a11 : a10;                                           \
    float hnew = fast_tanh((L ? v1 : v0) + mybias);                            \
    hlast = hnew;                                                              \
    if ((T) > 0 || L == 0) *(_Float16*)(waddr + (WB)) = (_Float16)hnew;        \
    if (L == 1 && (T) >= TT - FF + 1)                                          \
      *(_Float16*)(tailaddr + ((T) - (TT - FF + 1)) * (HH * 2)) =              \
          (_Float16)hnew;                                                      \
    if ((tid & 7) == 0)                                                        \
      *(_Float16*)(lb + (WB) + XOFF + (xi >> 4) * XSL + (xi & 15) * 2) =       \
          (_Float16)xn;                                                        \
    __syncthreads();                                                           \
  }

__global__ __attribute__((amdgpu_flat_work_group_size(512, 512),
                          amdgpu_waves_per_eu(2, 2)))
void rnn_fused(const float* __restrict__ x, const float* __restrict__ hidden,
               const float* __restrict__ Wih0, const float* __restrict__ Whh0,
               const float* __restrict__ bih0, const float* __restrict__ bhh0,
               const float* __restrict__ Wih1, const float* __restrict__ Whh1,
               const float* __restrict__ bih1, const float* __restrict__ bhh1,
               const float* __restrict__ fcW, const float* __restrict__ fcb,
               float* __restrict__ out)
{
  const int tid = threadIdx.x;
  const int b = blockIdx.x;
  const int lane = tid & 63;
  const int kg = lane & 3;       // K-group 0..3 (64 h-elems / 16 x-elems each)
  const int rg = tid >> 2;       // row-group 0..127
  const int j0 = rg * 2;         // first of 2 owned rows
  const int L = kg >> 1;         // commit layer of this lane
  const int cj = j0 + (kg & 1);  // committed row
  const int xi = tid >> 3;       // x element for (tid&7)==0 lanes

  __shared__ __align__(16) char lds[LDSBYTES];
  char* lb = (char*)lds;

  // ---- weights for rows j0,j0+1, K-slice kg -> 208 ints ----
  int w0x[2][8], w0h[2][32], w1g[2][32], w1h[2][32];
#pragma unroll
  for (int r = 0; r < 2; ++r) {
    const float* p0 = Wih0 + (size_t)(j0 + r) * II + kg * 16;
#pragma unroll
    for (int m = 0; m < 8; ++m) w0x[r][m] = pk2i(p0 + 2 * m);
    const float* p1 = Whh0 + (size_t)(j0 + r) * HH + kg * 64;
#pragma unroll
    for (int m = 0; m < 32; ++m) w0h[r][m] = pk2i(p1 + 2 * m);
    const float* p2 = Wih1 + (size_t)(j0 + r) * HH + kg * 64;
#pragma unroll
    for (int m = 0; m < 32; ++m) w1g[r][m] = pk2i(p2 + 2 * m);
    const float* p3 = Whh1 + (size_t)(j0 + r) * HH + kg * 64;
#pragma unroll
    for (int m = 0; m < 32; ++m) w1h[r][m] = pk2i(p3 + 2 * m);
  }
  // guard against remat of the global loads between init and loop
#pragma unroll
  for (int r = 0; r < 2; ++r) {
#pragma unroll
    for (int m = 0; m < 8; ++m) asm volatile("" : "+v"(w0x[r][m]));
#pragma unroll
    for (int m = 0; m < 32; ++m) {
      asm volatile("" : "+v"(w0h[r][m]));
      asm volatile("" : "+v"(w1g[r][m]));
      asm volatile("" : "+v"(w1h[r][m]));
    }
  }
  float mybias = L ? (bih1[cj] + bhh1[cj]) : (bih0[cj] + bhh0[cj]);
  asm volatile("" : "+v"(mybias));

  // ---- loop-invariant LDS addresses ----
  const char* h0addr = lb + kg * HSL;         // +RB (+H1OFF) +c*16
  const char* xaddr = lb + XOFF + kg * XSL;   // +RB +c*16
  char* waddr = lb + (L ? H1OFF : 0) + (cj >> 6) * HSL + (cj & 63) * 2;  // +WB
  char* tailaddr = lb + TAILOFF + cj * 2;     // +f*512, L==1 lanes only

  // ---- init: BUF0 <- {h0_init, h1_init, x_0}; BUF1.h1 <- h1_init
  // (step 0 commits h0_0+x_1 to BUF1 but skips h1; step 1 must read true
  //  h1_init from BUF1) ----
  if (tid < HH) {
    char* p = lb + (tid >> 6) * HSL + (tid & 63) * 2;
    _Float16 h0v = (_Float16)hidden[(size_t)b * HH + tid];
    _Float16 h1v = (_Float16)hidden[(size_t)(BB + b) * HH + tid];
    *(_Float16*)(p + BUF0) = h0v;
    *(_Float16*)(p + BUF0 + H1OFF) = h1v;
    *(_Float16*)(p + BUF1 + H1OFF) = h1v;
  }
  const float* xrow = x + (size_t)b * TT * II;
  if (tid < II)
    *(_Float16*)(lb + BUF0 + XOFF + (tid >> 4) * XSL + (tid & 15) * 2) =
        (_Float16)xrow[tid];
  float hlast = 0.f, h1last = 0.f;
  __syncthreads();

  // ---- main loop: 1 barrier/step, unroll x2 so RB/WB are immediates ----
#pragma unroll 1
  for (int t = 0; t < TT; t += 2) {
    RNN_STEP(t, BUF0, BUF1)
    RNN_STEP(t + 1, BUF1, BUF0)
  }

  // ---- epilogue: h1_{TT-1} from BUF0 (holds h0_{TT-1}, h1_{TT-2}) ----
  {
    float a10 = 0.f, a11 = 0.f;
#pragma unroll
    for (int c = 0; c < 8; ++c) {
      const int4 v = *(const int4*)(h0addr + BUF0 + c * 16);
      adot(a10, v.x, w1g[0][4 * c + 0]); adot(a10, v.y, w1g[0][4 * c + 1]);
      adot(a10, v.z, w1g[0][4 * c + 2]); adot(a10, v.w, w1g[0][4 * c + 3]);
      adot(a11, v.x, w1g[1][4 * c + 0]); adot(a11, v.y, w1g[1][4 * c + 1]);
      adot(a11, v.z, w1g[1][4 * c + 2]); adot(a11, v.w, w1g[1][4 * c + 3]);
    }
#pragma unroll
    for (int c = 0; c < 8; ++c) {
      const int4 v = *(const int4*)(h0addr + BUF0 + H1OFF + c * 16);
      adot(a10, v.x, w1h[0][4 * c + 0]); adot(a10, v.y, w1h[0][4 * c + 1]);
      adot(a10, v.z, w1h[0][4 * c + 2]); adot(a10, v.w, w1h[0][4 * c + 3]);
      adot(a11, v.x, w1h[1][4 * c + 0]); adot(a11, v.y, w1h[1][4 * c + 1]);
      adot(a11, v.z, w1h[1][4 * c + 2]); adot(a11, v.w, w1h[1][4 * c + 3]);
    }
    a10 = dpp_add<0xB1>(a10); a10 = dpp_add<0x4E>(a10);
    a11 = dpp_add<0xB1>(a11); a11 = dpp_add<0x4E>(a11);
    float v1 = (kg & 1) ? a11 : a10;
    float h1e = fast_tanh(v1 + mybias);  // valid on L==1 lanes
    h1last = h1e;
    if (L == 1) *(_Float16*)(tailaddr + (FF - 1) * (HH * 2)) = (_Float16)h1e;
  }
  __syncthreads();

  // ---- new_hidden [2,B,H] f32 at flat offset B*F*O ----
  if (L == 0) out[BB * FF * OO + (size_t)b * HH + cj] = hlast;
  else        out[BB * FF * OO + (size_t)(BB + b) * HH + cj] = h1last;

  // ---- out[b,f,o] = tail[f] . fcW[o,:] + fcb[o]  ([B,F,O] f32) ----
  const int o = tid & 63;
  const int fg = tid >> 6;  // f = 2*fg, 2*fg+1
  const _Float16* tp = (const _Float16*)(lb + TAILOFF);
  float acc0 = 0.f, acc1 = 0.f;
  const float* wrow = fcW + o * HH;
  for (int c = 0; c < HH / 8; ++c) {
    float wv[8];
#pragma unroll
    for (int k = 0; k < 8; ++k) wv[k] = wrow[8 * c + k];
    h8 q0 = *(const h8*)(tp + (2 * fg) * HH + 8 * c);
    h8 q1 = *(const h8*)(tp + (2 * fg + 1) * HH + 8 * c);
#pragma unroll
    for (int e = 0; e < 8; ++e) {
      acc0 += (float)q0[e] * wv[e];
      acc1 += (float)q1[e] * wv[e];
    }
  }
  const float bo = fcb[o];
  out[((size_t)b * FF + 2 * fg) * OO + o] = acc0 + bo;
  out[((size_t)b * FF + 2 * fg + 1) * OO + o] = acc1 + bo;
}

extern "C" void kernel_launch(void* const* d_in, const int* in_sizes, int n_in,
                              void* d_out, int out_size, void* d_ws, size_t ws_size,
                              hipStream_t stream) {
  (void)in_sizes; (void)n_in; (void)d_ws; (void)ws_size; (void)out_size;
  rnn_fused<<<dim3(BB), dim3(512), 0, stream>>>(
      (const float*)d_in[0],  (const float*)d_in[1],
      (const float*)d_in[2],  (const float*)d_in[3],
      (const float*)d_in[4],  (const float*)d_in[5],
      (const float*)d_in[6],  (const float*)d_in[7],
      (const float*)d_in[8],  (const float*)d_in[9],
      (const float*)d_in[10], (const float*)d_in[11],
      (float*)d_out);
}